// Round 1
// baseline (172.746 us; speedup 1.0000x reference)
//
#include <hip/hip_runtime.h>
#include <math.h>

#define BATCHES 32
#define NPTS 65536
#define CH 14
#define BLOCKS_PER_BATCH 32
#define THREADS 256
#define PPB (NPTS / BLOCKS_PER_BATCH)   // 2048 points per block

// Kernel 1: per-batch 9-way moment reduction.
// Layout: gaussians[b][n][14]; point record = 56 bytes, we read ch 0..2.
__global__ __launch_bounds__(THREADS) void moments_kernel(
    const float* __restrict__ g, double* __restrict__ ws) {
    const int b   = blockIdx.x / BLOCKS_PER_BATCH;
    const int blk = blockIdx.x % BLOCKS_PER_BATCH;
    const size_t base_pt = (size_t)b * NPTS + (size_t)blk * PPB;

    float sx = 0.f, sy = 0.f, sz = 0.f;
    float sxx = 0.f, syy = 0.f, szz = 0.f;
    float sxy = 0.f, sxz = 0.f, syz = 0.f;

    for (int i = threadIdx.x; i < PPB; i += THREADS) {
        const float* p = g + (base_pt + (size_t)i) * CH;
        // byte offset = 56 * point -> 8B aligned: float2 + float
        float2 xy = *(const float2*)p;
        float z = p[2];
        float x = xy.x, y = xy.y;
        sx += x;    sy += y;    sz += z;
        sxx += x*x; syy += y*y; szz += z*z;
        sxy += x*y; sxz += x*z; syz += y*z;
    }

    float vals[9] = {sx, sy, sz, sxx, syy, szz, sxy, sxz, syz};
#pragma unroll
    for (int k = 0; k < 9; ++k) {
        float v = vals[k];
#pragma unroll
        for (int off = 32; off >= 1; off >>= 1)
            v += __shfl_down(v, off, 64);
        vals[k] = v;
    }

    __shared__ float red[THREADS / 64][9];
    const int wave = threadIdx.x >> 6;
    const int lane = threadIdx.x & 63;
    if (lane == 0) {
#pragma unroll
        for (int k = 0; k < 9; ++k) red[wave][k] = vals[k];
    }
    __syncthreads();
    if (threadIdx.x == 0) {
#pragma unroll
        for (int k = 0; k < 9; ++k) {
            float s = red[0][k] + red[1][k] + red[2][k] + red[3][k];
            atomicAdd(&ws[b * 9 + k], (double)s);
        }
    }
}

// Kernel 2: per-batch 3x3 symmetric eigensolve (fp64 closed form) + final mean.
__global__ __launch_bounds__(64) void finish_kernel(
    const double* __restrict__ ws, float* __restrict__ out) {
    __shared__ double logs[BATCHES];
    const int b = threadIdx.x;
    if (b < BATCHES) {
        const double* s = ws + b * 9;
        const double invN = 1.0 / (double)NPTS;
        double mx = s[0] * invN, my = s[1] * invN, mz = s[2] * invN;
        double a00 = s[3] * invN - mx * mx;
        double a11 = s[4] * invN - my * my;
        double a22 = s[5] * invN - mz * mz;
        double a01 = s[6] * invN - mx * my;
        double a02 = s[7] * invN - mx * mz;
        double a12 = s[8] * invN - my * mz;
        // _sanitize: clamp to +-1e6 (inputs finite; NaN path not reachable here)
        const double CL = 1e6;
        a00 = fmin(fmax(a00, -CL), CL); a11 = fmin(fmax(a11, -CL), CL);
        a22 = fmin(fmax(a22, -CL), CL); a01 = fmin(fmax(a01, -CL), CL);
        a02 = fmin(fmax(a02, -CL), CL); a12 = fmin(fmax(a12, -CL), CL);

        // closed-form eigenvalues of symmetric 3x3
        double q  = (a00 + a11 + a22) / 3.0;
        double p1 = a01 * a01 + a02 * a02 + a12 * a12;
        double b00 = a00 - q, b11 = a11 - q, b22 = a22 - q;
        double p2 = b00 * b00 + b11 * b11 + b22 * b22 + 2.0 * p1;
        double eigmax, eigmin;
        if (p2 <= 0.0) {
            eigmax = eigmin = q;
        } else {
            double p  = sqrt(p2 / 6.0);
            double ip = 1.0 / p;
            double c00 = b00 * ip, c11 = b11 * ip, c22 = b22 * ip;
            double c01 = a01 * ip, c02 = a02 * ip, c12 = a12 * ip;
            double detB = c00 * (c11 * c22 - c12 * c12)
                        - c01 * (c01 * c22 - c12 * c02)
                        + c02 * (c01 * c12 - c11 * c02);
            double r = detB * 0.5;
            r = fmin(1.0, fmax(-1.0, r));
            double phi = acos(r) / 3.0;
            eigmax = q + 2.0 * p * cos(phi);
            eigmin = q + 2.0 * p * cos(phi + 2.0943951023931953);  // +2pi/3
        }
        double maxe = fmax(fmin(eigmax, 1e6), 1e-6);
        double mine = fmax(fmin(eigmin, 1e6), 1e-6);
        double ratio = maxe / mine;
        ratio = fmin(fmax(ratio, 1.0), 1e6);
        logs[b] = log(ratio);
    }
    __syncthreads();
    if (threadIdx.x == 0) {
        double acc = 0.0;
#pragma unroll
        for (int i = 0; i < BATCHES; ++i) acc += logs[i];
        out[0] = (float)(-acc / (double)BATCHES);
    }
}

extern "C" void kernel_launch(void* const* d_in, const int* in_sizes, int n_in,
                              void* d_out, int out_size, void* d_ws, size_t ws_size,
                              hipStream_t stream) {
    const float* g = (const float*)d_in[0];
    float* out = (float*)d_out;
    double* ws = (double*)d_ws;

    // zero the 32*9 double accumulators (ws is poisoned 0xAA before each call)
    hipMemsetAsync(ws, 0, BATCHES * 9 * sizeof(double), stream);

    moments_kernel<<<BATCHES * BLOCKS_PER_BATCH, THREADS, 0, stream>>>(g, ws);
    finish_kernel<<<1, 64, 0, stream>>>(ws, out);
}